// Round 4
// baseline (207.075 us; speedup 1.0000x reference)
//
#include <hip/hip_runtime.h>
#include <stdint.h>

typedef unsigned short u16;
typedef __attribute__((ext_vector_type(8))) short short8;
typedef __attribute__((ext_vector_type(4))) short short4v;
typedef __attribute__((ext_vector_type(4))) float f32x4;

#define LOG2E 1.44269504088896340736f

#define Bb 8
#define NSEQ 1024
#define DIMC 768
#define NH 12
#define DH 64
#define INNER 768
#define MTOT (Bb*NSEQ)      /* 8192 */
#define QKVN (3*INNER)      /* 2304 */
#define HEADS_TOT (Bb*NH)   /* 96 */
#define QKV_PART ((size_t)Bb*NH*NSEQ*DH)  /* 786432 elems per Q/K/V part */

static __device__ inline u16 f2bf(float f) {
    uint32_t u = __builtin_bit_cast(uint32_t, f);
    uint32_t r = (u + 0x7fffu + ((u >> 16) & 1u)) >> 16;
    return (u16)r;
}

// pack two f32 -> bf16 pair (round-half-up) in 3 VALU ops via v_perm
static __device__ __forceinline__ uint32_t pkbf(float f0, float f1) {
    uint32_t u0 = __builtin_bit_cast(uint32_t, f0) + 0x8000u;
    uint32_t u1 = __builtin_bit_cast(uint32_t, f1) + 0x8000u;
    return __builtin_amdgcn_perm(u1, u0, 0x07060302u);  // [u0b2,u0b3,u1b2,u1b3]
}

// 16x16x16 bf16 MFMA (K=16): B-operand k-packing (quad*4+j) matches the
// C-layout of a 16x16 MFMA output — lets S^T feed PV without an LDS round-trip.
#if __has_builtin(__builtin_amdgcn_mfma_f32_16x16x16bf16_1k)
static __device__ __forceinline__ f32x4 mfma16(short4v a, short4v b, f32x4 c) {
    return __builtin_amdgcn_mfma_f32_16x16x16bf16_1k(a, b, c, 0, 0, 0);
}
#else
static __device__ __forceinline__ f32x4 mfma16(short4v a, short4v b, f32x4 c) {
    asm volatile("v_mfma_f32_16x16x16_bf16 %0, %1, %2, %0\n\ts_nop 7\n\ts_nop 7"
                 : "+v"(c) : "v"(a), "v"(b));
    return c;
}
#endif

// ---- async global->LDS, 16B per lane; lds dest = wave-uniform base + lane*16 ----
typedef __attribute__((address_space(1))) const void gas_void;
typedef __attribute__((address_space(3))) void las_void;
static __device__ __forceinline__ void async16(u16* lds, const u16* g) {
    __builtin_amdgcn_global_load_lds((gas_void*)(uintptr_t)g,
                                     (las_void*)(uintptr_t)lds, 16, 0, 0);
}

// ---------------- fused fp32 -> bf16 conversion (single dispatch) ----------------
#define NX8  786432
#define NWQ8 221184
#define NWP8 73728
#define NCVT (NX8 + NWQ8 + NWP8)  /* 1081344 = 4224 * 256 */
__global__ __launch_bounds__(256) void cvt_all(const float* __restrict__ x,
                                               const float* __restrict__ wq,
                                               const float* __restrict__ wp,
                                               u16* __restrict__ xb,
                                               u16* __restrict__ wqb,
                                               u16* __restrict__ wpb) {
    int i = blockIdx.x * 256 + threadIdx.x;
    const float* s; u16* d; int j;
    if (i < NX8) { s = x; d = xb; j = i; }
    else if (i < NX8 + NWQ8) { s = wq; d = wqb; j = i - NX8; }
    else { s = wp; d = wpb; j = i - NX8 - NWQ8; }
    const float4* s4 = (const float4*)s;
    float4 a = s4[2 * j], b = s4[2 * j + 1];
    float v[8] = {a.x, a.y, a.z, a.w, b.x, b.y, b.z, b.w};
    u16 o[8];
#pragma unroll
    for (int t = 0; t < 8; t++) o[t] = f2bf(v[t]);
    ((uint4*)d)[j] = *(const uint4*)o;
}

// ---------------- QKV GEMM: 512 threads, BM=128 x BN=256, BK=32 ----------------
// qkv = x(8192x768) * w_qkv(2304x768)^T, scatter-store bf16:
//   Q pre-scaled by 0.125*log2(e); K [b,h,n,d]; V transposed [b,h,d,n]
#define BK 32
__global__ __launch_bounds__(512, 4) void gemm_qkv(const u16* __restrict__ A,
                                                   const u16* __restrict__ Bm,
                                                   u16* __restrict__ qkv) {
    __shared__ u16 As[128 * BK];   // 8 KB
    __shared__ u16 Bs[256 * BK];   // 16 KB
    const int tid = threadIdx.x;
    const int w = tid >> 6, lane = tid & 63, quad = lane >> 4, l16 = lane & 15;
    const int wr = w >> 2, wc = w & 3;           // 2 x 4 wave grid, 64x64 each
    const int m0 = blockIdx.y * 128;
    const int n0 = blockIdx.x * 256;
    const int K = DIMC;

    const int rl = lane >> 2, cc = lane & 3;
    // A staging: wave w stages rows w*16 .. w*16+15 (one async16)
    const int ra = w * 16 + rl;
    const u16* agp = A + (size_t)(m0 + ra) * K + ((cc - ((ra >> 1) & 3)) & 3) * 8;
    u16* alp = As + (w * 16) * BK;
    // B staging: wave w stages rows w*32+j*16 (two async16)
    const u16* bgp[2]; u16* blp[2];
#pragma unroll
    for (int j = 0; j < 2; j++) {
        int rb = w * 32 + j * 16 + rl;
        bgp[j] = Bm + (size_t)(n0 + rb) * K + ((cc - ((rb >> 1) & 3)) & 3) * 8;
        blp[j] = Bs + (w * 32 + j * 16) * BK;
    }

    const int swz = ((quad + ((l16 >> 1) & 3)) & 3) * 8;
    int aoff[4], boff[4];
#pragma unroll
    for (int t = 0; t < 4; t++) {
        aoff[t] = (wr * 64 + t * 16 + l16) * BK + swz;
        boff[t] = (wc * 64 + t * 16 + l16) * BK + swz;
    }

    f32x4 acc[4][4] = {};
    for (int kt = 0; kt < K; kt += BK) {
        __syncthreads();
        async16(alp, agp + kt);
        async16(blp[0], bgp[0] + kt);
        async16(blp[1], bgp[1] + kt);
        __syncthreads();
        short8 af[4], bf[4];
#pragma unroll
        for (int t = 0; t < 4; t++) af[t] = *(const short8*)(As + aoff[t]);
#pragma unroll
        for (int t = 0; t < 4; t++) bf[t] = *(const short8*)(Bs + boff[t]);
#pragma unroll
        for (int mt = 0; mt < 4; mt++)
#pragma unroll
            for (int nt = 0; nt < 4; nt++)
                acc[mt][nt] = __builtin_amdgcn_mfma_f32_16x16x32_bf16(af[mt], bf[nt],
                                                                      acc[mt][nt], 0, 0, 0);
    }

#pragma unroll
    for (int nt = 0; nt < 4; nt++) {
        int o = n0 + wc * 64 + nt * 16 + l16;
        int which = o / 768;
        int rem = o - which * 768;
        int h = rem >> 6, d = rem & 63;
        if (which == 2) {
            u16* vt = qkv + 2 * QKV_PART;
#pragma unroll
            for (int mt = 0; mt < 4; mt++) {
                int m = m0 + wr * 64 + mt * 16 + quad * 4;
                int bb = m >> 10, ns = m & 1023;
                alignas(8) u16 pk[4];
#pragma unroll
                for (int r = 0; r < 4; r++) pk[r] = f2bf(acc[mt][nt][r]);
                *(uint2*)(vt + ((size_t)(bb * NH + h) * DH + d) * NSEQ + ns) =
                    *(const uint2*)pk;
            }
        } else {
            float sc = (which == 0) ? (0.125f * LOG2E) : 1.0f;
#pragma unroll
            for (int mt = 0; mt < 4; mt++)
#pragma unroll
                for (int r = 0; r < 4; r++) {
                    int m = m0 + wr * 64 + mt * 16 + quad * 4 + r;
                    int bb = m >> 10, ns = m & 1023;
                    size_t idx = (size_t)which * QKV_PART +
                                 (((size_t)(bb * NH + h) * NSEQ + ns) << 6) + d;
                    qkv[idx] = f2bf(acc[mt][nt][r] * sc);
                }
        }
    }
}

// ---------------- proj GEMM: 256 threads, 128x128 tile, fp32 out ----------------
__global__ __launch_bounds__(256) void gemm_proj(const u16* __restrict__ A,
                                                 const u16* __restrict__ Bm,
                                                 float* __restrict__ Co) {
    __shared__ u16 As[128 * BK];
    __shared__ u16 Bs[128 * BK];
    const int tid = threadIdx.x;
    const int w = tid >> 6, lane = tid & 63, quad = lane >> 4, l16 = lane & 15;
    const int wr = w >> 1, wc = w & 1;
    const int m0 = blockIdx.y * 128;
    const int n0 = blockIdx.x * 128;
    const int K = INNER, N = DIMC;

    const int rl = lane >> 2, cc = lane & 3;
    const u16* ag[2]; const u16* bg[2]; u16* al[2]; u16* bl[2];
#pragma unroll
    for (int j = 0; j < 2; j++) {
        int r = w * 32 + j * 16 + rl;
        int c = ((cc - ((r >> 1) & 3)) & 3) * 8;
        ag[j] = A + (size_t)(m0 + r) * K + c;
        bg[j] = Bm + (size_t)(n0 + r) * K + c;
        al[j] = As + (w * 32 + j * 16) * BK;
        bl[j] = Bs + (w * 32 + j * 16) * BK;
    }
    const int swz = ((quad + ((l16 >> 1) & 3)) & 3) * 8;
    int aoff[4], boff[4];
#pragma unroll
    for (int t = 0; t < 4; t++) {
        aoff[t] = (wr * 64 + t * 16 + l16) * BK + swz;
        boff[t] = (wc * 64 + t * 16 + l16) * BK + swz;
    }

    f32x4 acc[4][4] = {};
    for (int kt = 0; kt < K; kt += BK) {
        __syncthreads();
#pragma unroll
        for (int j = 0; j < 2; j++) {
            async16(al[j], ag[j] + kt);
            async16(bl[j], bg[j] + kt);
        }
        __syncthreads();
        short8 af[4], bf[4];
#pragma unroll
        for (int t = 0; t < 4; t++) af[t] = *(const short8*)(As + aoff[t]);
#pragma unroll
        for (int t = 0; t < 4; t++) bf[t] = *(const short8*)(Bs + boff[t]);
#pragma unroll
        for (int mt = 0; mt < 4; mt++)
#pragma unroll
            for (int nt = 0; nt < 4; nt++)
                acc[mt][nt] = __builtin_amdgcn_mfma_f32_16x16x32_bf16(af[mt], bf[nt],
                                                                      acc[mt][nt], 0, 0, 0);
    }
#pragma unroll
    for (int mt = 0; mt < 4; mt++)
#pragma unroll
        for (int nt = 0; nt < 4; nt++) {
            int o = n0 + wc * 64 + nt * 16 + l16;
#pragma unroll
            for (int r = 0; r < 4; r++) {
                int m = m0 + wr * 64 + mt * 16 + quad * 4 + r;
                Co[(size_t)m * N + o] = acc[mt][nt][r];
            }
        }
}

// ---------------- Flash attention v4: S^T + in-register P, O^T accumulate ----------------
// Per (head, 128 Q-rows) block, 4 waves x 32 rows. S^T = K*Q^T (C-layout: q=l16,
// k=quad*4+r) feeds 16x16x16 PV MFMAs directly as the B operand; O^T[d][q] in C-layout.
__global__ __launch_bounds__(256) void attn_kernel(const u16* __restrict__ qkv,
                                                   u16* __restrict__ attn) {
    __shared__ u16 Ks[64 * 64];   // rows: key pos, cols: d  (rotated 16B chunks)
    __shared__ u16 Vs[64 * 64];   // rows: d, cols: key pos  (rotated 16B chunks)

    const int tid = threadIdx.x;
    const int w = tid >> 6, lane = tid & 63, quad = lane >> 4, l16 = lane & 15;
    const int bh = blockIdx.y, qt = blockIdx.x;
    const size_t headoff = (size_t)bh * NSEQ * DH;
    const u16* Qp = qkv + headoff;
    const u16* Kp = qkv + QKV_PART + headoff;
    const u16* Vtp = qkv + 2 * QKV_PART + headoff;
    const int q0 = qt * 128 + w * 32;

    const int rl8 = lane >> 3, cc8 = lane & 7;
    const u16* kg[2]; const u16* vg[2]; u16* kl[2]; u16* vl[2];
#pragma unroll
    for (int j = 0; j < 2; j++) {
        int r = w * 16 + j * 8 + rl8;
        int c = ((cc8 - r) & 7) * 8;
        kg[j] = Kp + (size_t)r * DH + c;
        vg[j] = Vtp + (size_t)r * NSEQ + c;
        kl[j] = Ks + (w * 16 + j * 8) * 64;
        vl[j] = Vs + (w * 16 + j * 8) * 64;
    }

    const int sw0 = ((quad + l16) & 7) * 8;       // K-frag d-chunk quad
    const int sw1 = ((quad + 4 + l16) & 7) * 8;   // K-frag d-chunk quad+4

    short8 qf[2][2];
#pragma unroll
    for (int mf = 0; mf < 2; mf++) {
        qf[mf][0] = *(const short8*)(Qp + (size_t)(q0 + mf * 16 + l16) * DH + quad * 8);
        qf[mf][1] = *(const short8*)(Qp + (size_t)(q0 + mf * 16 + l16) * DH + 32 + quad * 8);
    }

    f32x4 oacc[2][4] = {};          // O^T[d = nt2*16+quad*4+r][q = q0+mf*16+l16]
    float lsum[2] = {0.f, 0.f};     // per-lane partial sum for q = l16

    for (int kt = 0; kt < NSEQ; kt += 64) {
        __syncthreads();
#pragma unroll
        for (int j = 0; j < 2; j++) {
            async16(kl[j], kg[j] + (size_t)kt * DH);
            async16(vl[j], vg[j] + kt);
        }
        __syncthreads();

        // K fragments (A-operand of S^T): row = key 16-group nt + l16
        short8 kf[4][2];
#pragma unroll
        for (int nt = 0; nt < 4; nt++) {
            const u16* kr = Ks + (nt * 16 + l16) * 64;
            kf[nt][0] = *(const short8*)(kr + sw0);
            kf[nt][1] = *(const short8*)(kr + sw1);
        }
        // V fragments (A-operand of PV, 16x16x16): V^T[d=nt2*16+l16][k=c*16+quad*4 ..+3]
        short4v vf[4][4];
#pragma unroll
        for (int nt2 = 0; nt2 < 4; nt2++) {
            int row = nt2 * 16 + l16;
#pragma unroll
            for (int c = 0; c < 4; c++) {
                int off = row * 64 + (((c * 2 + (quad >> 1) + row) & 7) << 3) + (quad & 1) * 4;
                vf[nt2][c] = *(const short4v*)(Vs + off);
            }
        }

#pragma unroll
        for (int mf = 0; mf < 2; mf++) {
            // S^T = K * Q^T : lane holds q=l16, key = kt + nt*16 + quad*4 + r
            f32x4 st[4];
#pragma unroll
            for (int nt = 0; nt < 4; nt++) {
                f32x4 z = {};
                z = __builtin_amdgcn_mfma_f32_16x16x32_bf16(kf[nt][0], qf[mf][0], z, 0, 0, 0);
                z = __builtin_amdgcn_mfma_f32_16x16x32_bf16(kf[nt][1], qf[mf][1], z, 0, 0, 0);
                st[nt] = z;
            }
            // P = exp2(S^T) in-register, pack to bf16 B-fragments
            short4v pf[4];
#pragma unroll
            for (int c = 0; c < 4; c++) {
                float p0 = __builtin_amdgcn_exp2f(st[c][0]);
                float p1 = __builtin_amdgcn_exp2f(st[c][1]);
                float p2 = __builtin_amdgcn_exp2f(st[c][2]);
                float p3 = __builtin_amdgcn_exp2f(st[c][3]);
                lsum[mf] += (p0 + p1) + (p2 + p3);
                uint2 u = {pkbf(p0, p1), pkbf(p2, p3)};
                pf[c] = __builtin_bit_cast(short4v, u);
            }
            // O^T += V^T * P^T  (16x16x16 per (d-group, k-chunk))
#pragma unroll
            for (int nt2 = 0; nt2 < 4; nt2++)
#pragma unroll
                for (int c = 0; c < 4; c++)
                    oacc[mf][nt2] = mfma16(vf[nt2][c], pf[c], oacc[mf][nt2]);
        }
    }

    // reduce lsum across the 4 quads (lanes sharing l16) and invert
#pragma unroll
    for (int mf = 0; mf < 2; mf++) {
        float v = lsum[mf];
        v += __shfl_xor(v, 16);
        v += __shfl_xor(v, 32);
        lsum[mf] = 1.0f / v;
    }

    // epilogue: attn[(b*N + q)*768 + h*64 + d]; lane: q=l16(+mf*16+q0), d=nt2*16+quad*4+r
    const int b = bh / NH, h = bh - (bh / NH) * NH;
#pragma unroll
    for (int mf = 0; mf < 2; mf++) {
        int q = q0 + mf * 16 + l16;
        float inv = lsum[mf];
#pragma unroll
        for (int nt2 = 0; nt2 < 4; nt2++) {
            uint2 u = {pkbf(oacc[mf][nt2][0] * inv, oacc[mf][nt2][1] * inv),
                       pkbf(oacc[mf][nt2][2] * inv, oacc[mf][nt2][3] * inv)};
            int d = nt2 * 16 + quad * 4;
            *(uint2*)(attn + ((size_t)(b * NSEQ + q)) * INNER + h * DH + d) = u;
        }
    }
}

extern "C" void kernel_launch(void* const* d_in, const int* in_sizes, int n_in,
                              void* d_out, int out_size, void* d_ws, size_t ws_size,
                              hipStream_t stream) {
    const float* x = (const float*)d_in[0];        // (8,1024,768)
    const float* w_qkv = (const float*)d_in[1];    // (2304,768)
    const float* w_proj = (const float*)d_in[2];   // (768,768)
    float* out = (float*)d_out;                    // (8,1024,768)

    u16* xb = (u16*)d_ws;                          // 6291456
    u16* wqkvb = xb + 6291456;                     // 1769472
    u16* wprojb = wqkvb + 1769472;                 // 589824
    u16* qkvb = wprojb + 589824;                   // 18874368 (Q,K: [b,h,n,d]; V: [b,h,d,n])
    u16* attnb = qkvb + 18874368;                  // 6291456  ((B,N,768))

    cvt_all<<<NCVT / 256, 256, 0, stream>>>(x, w_qkv, w_proj, xb, wqkvb, wprojb);

    dim3 g1(QKVN / 256, MTOT / 128);   // (9, 64), 512 threads
    gemm_qkv<<<g1, 512, 0, stream>>>(xb, wqkvb, qkvb);

    dim3 g2(NSEQ / 128, HEADS_TOT);    // (8, 96)
    attn_kernel<<<g2, 256, 0, stream>>>(qkvb, attnb);

    dim3 g3(INNER / 128, MTOT / 128);  // (6, 64)
    gemm_proj<<<g3, 256, 0, stream>>>(attnb, wprojb, out);
}